// Round 3
// baseline (1056.766 us; speedup 1.0000x reference)
//
#include <hip/hip_runtime.h>
#include <math.h>

#define B_SZ 32768
#define D_SZ 1024
#define R_SZ 64
#define E_SZ 4
#define L_SZ 3
#define NC   256          // E*R
#define TR   32           // rows per block
#define NTHR 256          // 4 waves

typedef __attribute__((ext_vector_type(8))) short bf16x8;
typedef __attribute__((ext_vector_type(4))) float f32x4;

__device__ __forceinline__ short f2bf(float f) {
    union { float f; unsigned u; } c; c.f = f;
    unsigned r = c.u + 0x7fffu + ((c.u >> 16) & 1u);   // round-to-nearest-even
    return (short)(r >> 16);
}

// Vt[l][c][d] = bf16(V[l][e][d][r]), c = e*64+r   (B-operand for v1: k=d contiguous)
__global__ __launch_bounds__(256) void pack_vt(const float* __restrict__ V,
                                               short* __restrict__ Vt) {
    int idx = blockIdx.x * 256 + threadIdx.x;          // L*256*1024
    int d = idx & 1023;
    int c = (idx >> 10) & 255;
    int l = idx >> 18;
    int e = c >> 6, r = c & 63;
    Vt[idx] = f2bf(V[((size_t)(l * E_SZ + e) * D_SZ + d) * R_SZ + r]);
}
// Ub[l][d][c] = bf16(U[l][e][d][s]), c = e*64+s    (B-operand for uv: k=c contiguous)
__global__ __launch_bounds__(256) void pack_ub(const float* __restrict__ U,
                                               short* __restrict__ Ub) {
    int idx = blockIdx.x * 256 + threadIdx.x;          // L*1024*256
    int c = idx & 255;
    int d = (idx >> 8) & 1023;
    int l = idx >> 18;
    int e = c >> 6, s = c & 63;
    Ub[idx] = f2bf(U[((size_t)(l * E_SZ + e) * D_SZ + d) * R_SZ + s]);
}
// Ct[l][e][s][r] = bf16(C[l][e][r][s])             (B-operand for v2: k=r contiguous)
__global__ __launch_bounds__(256) void pack_ct(const float* __restrict__ C,
                                               short* __restrict__ Ct) {
    int idx = blockIdx.x * 256 + threadIdx.x;          // L*4*64*64
    int r = idx & 63;
    int s = (idx >> 6) & 63;
    int le = idx >> 12;
    Ct[idx] = f2bf(C[((size_t)le * R_SZ + r) * R_SZ + s]);
}

// One fused cross layer: gating + v1 + v2 + w@U^T + epilogue, bf16 MFMA.
// TR=32 rows, 4 waves, grid=1024 -> 4 blocks/CU for latency hiding.
__global__ __launch_bounds__(NTHR, 4) void cross_layer(
    const float* xi,                       // may alias out (per-row in-place)
    const float* __restrict__ x0,
    const float* __restrict__ G,
    const short* __restrict__ Vt, const short* __restrict__ Ub,
    const short* __restrict__ Ct, const float* __restrict__ bias,
    float* out)
{
    __shared__ short xs[2 * TR * 136];   // double-buffered xi chunk (K=128), bf16
    __shared__ short wb[TR * 264];       // v1 then w, bf16
    __shared__ float ssc[TR * E_SZ];     // gating scores

    const int t = threadIdx.x;
    const int b0 = blockIdx.x * TR;
    const int lane = t & 63;
    const int wv = t >> 6;               // wave 0..3
    const int m = lane & 15;
    const int q = lane >> 4;

    const int srow = t >> 3;             // staging row 0..31
    const int sj = t & 7;                // staging col-octet
    const float* xrow = xi + (size_t)(b0 + srow) * D_SZ;

    float g[E_SZ] = {0.f, 0.f, 0.f, 0.f};   // gating partials (fused into staging)

    auto stage = [&](int kc, short* dstbuf) {
        const float* xp = xrow + kc * 128;
        short* dst = dstbuf + srow * 136;
        #pragma unroll
        for (int p = 0; p < 2; ++p) {
            const int col = sj * 8 + p * 64;
            float4 va = *(const float4*)(xp + col);
            float4 vb = *(const float4*)(xp + col + 4);
            #pragma unroll
            for (int e = 0; e < E_SZ; ++e) {
                float4 ga = *(const float4*)(G + e * D_SZ + kc * 128 + col);
                float4 gb = *(const float4*)(G + e * D_SZ + kc * 128 + col + 4);
                g[e] += va.x * ga.x + va.y * ga.y + va.z * ga.z + va.w * ga.w
                      + vb.x * gb.x + vb.y * gb.y + vb.z * gb.z + vb.w * gb.w;
            }
            bf16x8 s;
            s[0] = f2bf(va.x); s[1] = f2bf(va.y); s[2] = f2bf(va.z); s[3] = f2bf(va.w);
            s[4] = f2bf(vb.x); s[5] = f2bf(vb.y); s[6] = f2bf(vb.z); s[7] = f2bf(vb.w);
            *(bf16x8*)(dst + col) = s;
        }
    };

    // ---------------- phase V: v1 = tanh(xi @ V) with fused gating ----------------
    f32x4 accV[2][4];
    #pragma unroll
    for (int rt = 0; rt < 2; ++rt)
        #pragma unroll
        for (int ct = 0; ct < 4; ++ct) accV[rt][ct] = (f32x4){0.f, 0.f, 0.f, 0.f};
    const int cbase = wv * 64;

    stage(0, xs);
    __syncthreads();
    for (int kc = 0; kc < 8; ++kc) {
        const short* cur = xs + (kc & 1) * (TR * 136);
        if (kc < 7) stage(kc + 1, xs + ((kc & 1) ^ 1) * (TR * 136));
        #pragma unroll
        for (int ks = 0; ks < 4; ++ks) {
            bf16x8 a0 = *(const bf16x8*)(cur + m * 136 + ks * 32 + q * 8);
            bf16x8 a1 = *(const bf16x8*)(cur + (16 + m) * 136 + ks * 32 + q * 8);
            #pragma unroll
            for (int ct = 0; ct < 4; ++ct) {
                bf16x8 b = *(const bf16x8*)(Vt + (size_t)(cbase + ct * 16 + m) * D_SZ
                                            + kc * 128 + ks * 32 + q * 8);
                accV[0][ct] = __builtin_amdgcn_mfma_f32_16x16x32_bf16(a0, b, accV[0][ct], 0, 0, 0);
                accV[1][ct] = __builtin_amdgcn_mfma_f32_16x16x32_bf16(a1, b, accV[1][ct], 0, 0, 0);
            }
        }
        __syncthreads();
    }

    // gating reduce within 8-lane groups (one row per group)
    #pragma unroll
    for (int e = 0; e < E_SZ; ++e) {
        g[e] += __shfl_down(g[e], 4, 8);
        g[e] += __shfl_down(g[e], 2, 8);
        g[e] += __shfl_down(g[e], 1, 8);
    }
    if (sj == 0) {
        #pragma unroll
        for (int e = 0; e < E_SZ; ++e) ssc[srow * E_SZ + e] = g[e];
    }
    // tanh -> wb
    #pragma unroll
    for (int rt = 0; rt < 2; ++rt)
        #pragma unroll
        for (int ct = 0; ct < 4; ++ct)
            #pragma unroll
            for (int i = 0; i < 4; ++i) {
                int row = rt * 16 + q * 4 + i;
                int c = cbase + ct * 16 + m;
                wb[row * 264 + c] = f2bf(tanhf(accV[rt][ct][i]));
            }
    __syncthreads();   // barrier A: wb(v1) + raw scores visible

    // ---------------- phase C: v2 = tanh(v1 @ C_e), wave = expert ----------------
    const int e = wv;
    f32x4 accC[2][4];
    #pragma unroll
    for (int rt = 0; rt < 2; ++rt)
        #pragma unroll
        for (int st = 0; st < 4; ++st) accC[rt][st] = (f32x4){0.f, 0.f, 0.f, 0.f};
    #pragma unroll
    for (int ks = 0; ks < 2; ++ks) {
        bf16x8 a0 = *(const bf16x8*)(wb + m * 264 + e * 64 + ks * 32 + q * 8);
        bf16x8 a1 = *(const bf16x8*)(wb + (16 + m) * 264 + e * 64 + ks * 32 + q * 8);
        #pragma unroll
        for (int st = 0; st < 4; ++st) {
            bf16x8 b = *(const bf16x8*)(Ct + e * 4096 + (st * 16 + m) * 64 + ks * 32 + q * 8);
            accC[0][st] = __builtin_amdgcn_mfma_f32_16x16x32_bf16(a0, b, accC[0][st], 0, 0, 0);
            accC[1][st] = __builtin_amdgcn_mfma_f32_16x16x32_bf16(a1, b, accC[1][st], 0, 0, 0);
        }
    }
    // softmax (concurrent with other waves' C-MFMA; consumed only after barrier B)
    if (t < TR) {
        float l0 = ssc[t * 4 + 0], l1 = ssc[t * 4 + 1];
        float l2 = ssc[t * 4 + 2], l3 = ssc[t * 4 + 3];
        float mx = fmaxf(fmaxf(l0, l1), fmaxf(l2, l3));
        float e0 = __expf(l0 - mx), e1 = __expf(l1 - mx);
        float e2 = __expf(l2 - mx), e3 = __expf(l3 - mx);
        float inv = 1.f / (e0 + e1 + e2 + e3);
        ssc[t * 4 + 0] = e0 * inv; ssc[t * 4 + 1] = e1 * inv;
        ssc[t * 4 + 2] = e2 * inv; ssc[t * 4 + 3] = e3 * inv;
    }
    __syncthreads();   // barrier B: v1 reads done, softmax done
    #pragma unroll
    for (int rt = 0; rt < 2; ++rt)
        #pragma unroll
        for (int st = 0; st < 4; ++st)
            #pragma unroll
            for (int i = 0; i < 4; ++i) {
                int row = rt * 16 + q * 4 + i;
                int s = st * 16 + m;
                wb[row * 264 + e * 64 + s] =
                    f2bf(tanhf(accC[rt][st][i]) * ssc[row * E_SZ + e]);
            }
    __syncthreads();   // barrier C: wb(w) visible

    // ---------------- phase U: uv = w @ U^T + epilogue, two d-halves ----------------
    #pragma unroll
    for (int hf = 0; hf < 2; ++hf) {
        const int dbase = hf * 512 + wv * 128;
        f32x4 accU[2][8];
        #pragma unroll
        for (int rt = 0; rt < 2; ++rt)
            #pragma unroll
            for (int dt = 0; dt < 8; ++dt) accU[rt][dt] = (f32x4){0.f, 0.f, 0.f, 0.f};
        #pragma unroll
        for (int ks = 0; ks < 8; ++ks) {
            bf16x8 a0 = *(const bf16x8*)(wb + m * 264 + ks * 32 + q * 8);
            bf16x8 a1 = *(const bf16x8*)(wb + (16 + m) * 264 + ks * 32 + q * 8);
            #pragma unroll
            for (int dt = 0; dt < 8; ++dt) {
                bf16x8 b = *(const bf16x8*)(Ub + (size_t)(dbase + dt * 16 + m) * NC
                                            + ks * 32 + q * 8);
                accU[0][dt] = __builtin_amdgcn_mfma_f32_16x16x32_bf16(a0, b, accU[0][dt], 0, 0, 0);
                accU[1][dt] = __builtin_amdgcn_mfma_f32_16x16x32_bf16(a1, b, accU[1][dt], 0, 0, 0);
            }
        }
        #pragma unroll
        for (int dt = 0; dt < 8; ++dt) {
            int d = dbase + dt * 16 + m;
            float bv = bias[d];
            #pragma unroll
            for (int rt = 0; rt < 2; ++rt)
                #pragma unroll
                for (int i = 0; i < 4; ++i) {
                    int row = rt * 16 + q * 4 + i;
                    size_t off = (size_t)(b0 + row) * D_SZ + d;
                    out[off] = fmaf(x0[off], accU[rt][dt][i] + bv, xi[off]);
                }
        }
    }
}

extern "C" void kernel_launch(void* const* d_in, const int* in_sizes, int n_in,
                              void* d_out, int out_size, void* d_ws, size_t ws_size,
                              hipStream_t stream) {
    const float* x  = (const float*)d_in[0];
    const float* U  = (const float*)d_in[1];
    const float* V  = (const float*)d_in[2];
    const float* C  = (const float*)d_in[3];
    const float* bi = (const float*)d_in[4];
    const float* G  = (const float*)d_in[5];
    float* out = (float*)d_out;

    short* Vt = (short*)d_ws;                              // L*256*1024 bf16
    short* Ub = Vt + (size_t)L_SZ * NC * D_SZ;             // L*1024*256 bf16
    short* Ct = Ub + (size_t)L_SZ * D_SZ * NC;             // L*4*64*64 bf16

    pack_vt<<<(L_SZ * NC * D_SZ) / 256, 256, 0, stream>>>(V, Vt);
    pack_ub<<<(L_SZ * D_SZ * NC) / 256, 256, 0, stream>>>(U, Ub);
    pack_ct<<<(L_SZ * E_SZ * R_SZ * R_SZ) / 256, 256, 0, stream>>>(C, Ct);

    for (int l = 0; l < L_SZ; ++l) {
        const float* xil = (l == 0) ? x : out;
        cross_layer<<<B_SZ / TR, NTHR, 0, stream>>>(
            xil, x, G,
            Vt + (size_t)l * NC * D_SZ,
            Ub + (size_t)l * D_SZ * NC,
            Ct + (size_t)l * E_SZ * R_SZ * R_SZ,
            bi + (size_t)l * D_SZ,
            out);
    }
}